// Round 21
// baseline (347.412 us; speedup 1.0000x reference)
//
#include <hip/hip_runtime.h>
#include <stdint.h>

typedef unsigned short u16;
typedef float f32x4 __attribute__((ext_vector_type(4)));
typedef short short8 __attribute__((ext_vector_type(8)));  // 8 bf16 in 4 VGPRs

__device__ __forceinline__ u16 f2bf(float f) {
  union { float f; uint32_t u; } v; v.f = f;
  return (u16)((v.u + 0x7FFFu + ((v.u >> 16) & 1u)) >> 16);
}
__device__ __forceinline__ uint32_t pack2(u16 lo, u16 hi) {
  return (uint32_t)lo | ((uint32_t)hi << 16);
}
// Async global->LDS DMA, 16B/lane: LDS dest = wave-uniform base + lane*16,
// global src = per-lane address. Zero VGPR staging.
__device__ __forceinline__ void gld_lds16(const void* gsrc, void* ldst) {
  __builtin_amdgcn_global_load_lds(
      (const __attribute__((address_space(1))) unsigned int*)gsrc,
      (__attribute__((address_space(3))) unsigned int*)ldst, 16, 0, 0);
}

#define MFMA16(a, b, c) __builtin_amdgcn_mfma_f32_16x16x32_bf16((a), (b), (c), 0, 0, 0)

// ---------------------------------------------------------------------------
// Merged weight conversion: Wv (64K f4), Wo (64K f4), Wqk (8K f4, Q x log2e).
// One launch instead of three.
// ---------------------------------------------------------------------------
__global__ void conv_all(const float* __restrict__ Wv, const float* __restrict__ Wo,
                         const float* __restrict__ Wq, const float* __restrict__ Wk,
                         u16* __restrict__ Wvb, u16* __restrict__ Wob,
                         u16* __restrict__ Wqkb) {
  int i = blockIdx.x * blockDim.x + threadIdx.x;  // float4 index, 139264 total
  if (i >= 139264) return;
  const float LOG2E = 1.4426950408889634f;
  float4 v;
  u16* dst;
  int di;
  float s = 1.0f;
  if (i < 65536) {
    v = ((const float4*)Wv)[i]; dst = Wvb; di = i;
  } else if (i < 131072) {
    v = ((const float4*)Wo)[i - 65536]; dst = Wob; di = i - 65536;
  } else {
    int j = i - 131072;
    bool isQ = j < 4096;
    v = isQ ? ((const float4*)Wq)[j] : ((const float4*)Wk)[j - 4096];
    s = isQ ? LOG2E : 1.0f;
    dst = Wqkb; di = j;
  }
  uint2 p;
  p.x = pack2(f2bf(v.x * s), f2bf(v.y * s));
  p.y = pack2(f2bf(v.z * s), f2bf(v.w * s));
  ((uint2*)dst)[di] = p;
}

// ---------------------------------------------------------------------------
// Fused QKV projection, OG-SPLIT (round 20, verified): grid z in {0,1},
// 4 og-groups each; z=0 also computes Q/K. x prefetch ping-pong.
// ---------------------------------------------------------------------------
__global__ __launch_bounds__(256) void qkv_proj(
    const float* __restrict__ x, const u16* __restrict__ Wvb,
    const u16* __restrict__ Wqkb, const float* __restrict__ bv,
    const float* __restrict__ bq, const float* __restrict__ bk,
    u16* __restrict__ V2, u16* __restrict__ Qb, u16* __restrict__ Kb) {
  const int b = blockIdx.y, nb = blockIdx.x * 64;
  const int oh = blockIdx.z;               // og half: 0 -> og 0..3 (+QK), 1 -> og 4..7
  const int t = threadIdx.x, w = t >> 6, lane = t & 63, g = lane >> 4, l15 = lane & 15;
  const int wo = (w >> 1) * 32, wn = (w & 1) * 32;
  __shared__ __align__(16) u16 xT[64][64];  // row = n (128B rows), swizzled

  f32x4 zero4 = {0.f, 0.f, 0.f, 0.f};
  f32x4 acc[4][2][2];
#pragma unroll
  for (int og = 0; og < 4; ++og)
#pragma unroll
    for (int ot = 0; ot < 2; ++ot)
#pragma unroll
      for (int nt = 0; nt < 2; ++nt) acc[og][ot][nt] = zero4;
  f32x4 accq[2][2];
  accq[0][0] = zero4; accq[0][1] = zero4; accq[1][0] = zero4; accq[1][1] = zero4;

  const int cq4 = (t >> 4) * 4, n4 = (t & 15) * 4;
  const size_t xrow = (size_t)(b * 512) * 4096 + nb + n4;

  float4 cur0 = *(const float4*)&x[xrow + (size_t)(cq4 + 0) * 4096];
  float4 cur1 = *(const float4*)&x[xrow + (size_t)(cq4 + 1) * 4096];
  float4 cur2 = *(const float4*)&x[xrow + (size_t)(cq4 + 2) * 4096];
  float4 cur3 = *(const float4*)&x[xrow + (size_t)(cq4 + 3) * 4096];

#pragma unroll
  for (int ci = 0; ci < 8; ++ci) {
    const int c0 = ci * 64;
    float4 nxt0, nxt1, nxt2, nxt3;
    if (ci < 7) {
      nxt0 = *(const float4*)&x[xrow + (size_t)(c0 + 64 + cq4 + 0) * 4096];
      nxt1 = *(const float4*)&x[xrow + (size_t)(c0 + 64 + cq4 + 1) * 4096];
      nxt2 = *(const float4*)&x[xrow + (size_t)(c0 + 64 + cq4 + 2) * 4096];
      nxt3 = *(const float4*)&x[xrow + (size_t)(c0 + 64 + cq4 + 3) * 4096];
    }
    float rr[4][4];
    rr[0][0] = cur0.x; rr[0][1] = cur0.y; rr[0][2] = cur0.z; rr[0][3] = cur0.w;
    rr[1][0] = cur1.x; rr[1][1] = cur1.y; rr[1][2] = cur1.z; rr[1][3] = cur1.w;
    rr[2][0] = cur2.x; rr[2][1] = cur2.y; rr[2][2] = cur2.z; rr[2][3] = cur2.w;
    rr[3][0] = cur3.x; rr[3][1] = cur3.y; rr[3][2] = cur3.z; rr[3][3] = cur3.w;
#pragma unroll
    for (int k = 0; k < 4; ++k) {
      int row = n4 + k;
      uint2 pk;
      pk.x = pack2(f2bf(rr[0][k]), f2bf(rr[1][k]));
      pk.y = pack2(f2bf(rr[2][k]), f2bf(rr[3][k]));
      int byte = row * 128 + ((cq4 * 2) ^ ((row & 7) << 4));
      *(uint2*)((char*)&xT[0][0] + byte) = pk;
    }
    __syncthreads();

    short8 bb[2][2];
#pragma unroll
    for (int nt = 0; nt < 2; ++nt)
#pragma unroll
      for (int ks = 0; ks < 2; ++ks) {
        int row = wn + nt * 16 + l15;
        int byte = row * 128 + (((ks * 64) + (g * 16)) ^ ((row & 7) << 4));
        bb[nt][ks] = *(const short8*)((const char*)&xT[0][0] + byte);
      }
#pragma unroll
    for (int og = 0; og < 4; ++og) {
      short8 af[2][2];
#pragma unroll
      for (int ot = 0; ot < 2; ++ot)
#pragma unroll
        for (int ks = 0; ks < 2; ++ks)
          af[ot][ks] = *(const short8*)&Wvb[(size_t)((oh * 4 + og) * 64 + wo + ot * 16 + l15) * 512 + c0 + ks * 32 + g * 8];
#pragma unroll
      for (int ks = 0; ks < 2; ++ks)
#pragma unroll
        for (int ot = 0; ot < 2; ++ot)
#pragma unroll
          for (int nt = 0; nt < 2; ++nt)
            acc[og][ot][nt] = MFMA16(af[ot][ks], bb[nt][ks], acc[og][ot][nt]);
    }
    if (oh == 0) {
      short8 aq[2][2];
#pragma unroll
      for (int ot = 0; ot < 2; ++ot)
#pragma unroll
        for (int ks = 0; ks < 2; ++ks)
          aq[ot][ks] = *(const short8*)&Wqkb[(size_t)(wo + ot * 16 + l15) * 512 + c0 + ks * 32 + g * 8];
#pragma unroll
      for (int ks = 0; ks < 2; ++ks)
#pragma unroll
        for (int ot = 0; ot < 2; ++ot)
#pragma unroll
          for (int nt = 0; nt < 2; ++nt)
            accq[ot][nt] = MFMA16(aq[ot][ks], bb[nt][ks], accq[ot][nt]);
    }
    __syncthreads();
    if (ci < 7) { cur0 = nxt0; cur1 = nxt1; cur2 = nxt2; cur3 = nxt3; }
  }

  const size_t tbase = (size_t)b * 2097152 + (size_t)(nb >> 6) * 32768;
#pragma unroll
  for (int og = 0; og < 4; ++og)
#pragma unroll
    for (int ot = 0; ot < 2; ++ot)
#pragma unroll
      for (int nt = 0; nt < 2; ++nt)
#pragma unroll
        for (int r = 0; r < 4; ++r) {
          int o = (oh * 4 + og) * 64 + wo + ot * 16 + g * 4 + r;
          int kk = wn + nt * 16 + l15;
          int swz = ((kk * 2) ^ ((o & 7) << 4)) >> 1;
          V2[tbase + o * 64 + swz] = f2bf(acc[og][ot][nt][r] + bv[o]);
        }
  if (oh == 0) {
    const float LOG2E = 1.4426950408889634f;
#pragma unroll
    for (int ot = 0; ot < 2; ++ot)
#pragma unroll
      for (int nt = 0; nt < 2; ++nt)
#pragma unroll
        for (int r = 0; r < 4; ++r) {
          int o = wo + ot * 16 + g * 4 + r;   // 0..63: Q rows then K rows
          int n = nb + wn + nt * 16 + l15;
          if (o < 32) {
            Qb[((size_t)(b * 4096 + n)) * 32 + o] = f2bf(accq[ot][nt][r] + bq[o] * LOG2E);
          } else {
            Kb[((size_t)(b * 4096 + n)) * 32 + (o - 32)] = f2bf(accq[ot][nt][r] + bk[o - 32]);
          }
        }
  }
}

// ---------------------------------------------------------------------------
// Fused flash attention + Wo + residual, SINGLE-BARRIER pipeline.
// vs round 19 (251us, 2 barriers/iter): P double-buffered by tile parity
// (swizzled 128B rows, XOR (row&7)<<3 u16) -> mid-barrier removed; K(t+1)
// loads hoisted to iter start (L2 latency hides under pf-preread+PV).
// One end barrier covers all 4 race surfaces (P-write->pf-read,
// pf-read->P-overwrite, DMA->PV, PV->DMA-reissue). LDS = 160KB exactly;
// lsum overlays dead P2 at epilogue.
// ---------------------------------------------------------------------------
__global__ __launch_bounds__(512, 1) void attn_f(
    const u16* __restrict__ Qb, const u16* __restrict__ Kb,
    const u16* __restrict__ V2, const u16* __restrict__ Wob,
    const float* __restrict__ bo, const float* __restrict__ gamma,
    const float* __restrict__ x, float* __restrict__ out) {
  const int bid = blockIdx.x;
  const int b = bid & 7;                 // XCD-pinned batch
  const int qblk = (bid >> 3) * 128;
  const int t = threadIdx.x;
  const int w = t >> 6, lane = t & 63, g = lane >> 4, l15 = lane & 15;
  const int qg = w & 3, chh = w >> 2;    // SIMD i hosts (qg=i,chh=0)+(qg=i,chh=1)
  const int qbase = qblk + qg * 32;
  const int chb = chh * 256;

  __shared__ __align__(16) u16 Vlds[2][32768];   // 128KB; reused as AO
  __shared__ __align__(16) u16 P2[2][4][32][64]; // 32KB, dbuf by tile parity

  f32x4 zero4 = {0.f, 0.f, 0.f, 0.f};

  short8 qf[2];
  if (chh == 0) {
#pragma unroll
    for (int qt = 0; qt < 2; ++qt)
      qf[qt] = *(const short8*)&Qb[((size_t)(b * 4096 + qbase + qt * 16 + l15)) * 32 + g * 8];
  }

  f32x4 acc[2][16];
#pragma unroll
  for (int qt = 0; qt < 2; ++qt)
#pragma unroll
    for (int ct = 0; ct < 16; ++ct) acc[qt][ct] = zero4;
  float l_[2][4] = {{0.f, 0.f, 0.f, 0.f}, {0.f, 0.f, 0.f, 0.f}};

  const char* VBb = (const char*)(V2 + (size_t)b * 2097152);  // byte base
  const size_t kb0 = (size_t)b * 4096;

  // ---- prologue: DMA V(0); chh0 builds P(0) into P2[0] ----
  {
    const char* gsrc = VBb + w * 8192 + lane * 16;
    char* ldst = (char*)&Vlds[0][0] + w * 8192;
#pragma unroll
    for (int j = 0; j < 8; ++j) gld_lds16(gsrc + j * 1024, ldst + j * 1024);
  }
  if (chh == 0) {
    float rsv[2][4];
#pragma unroll
    for (int half = 0; half < 2; ++half) {
      short8 kfA = *(const short8*)&Kb[(kb0 + 0 + half * 32 + 0 + l15) * 32 + g * 8];
      short8 kfB = *(const short8*)&Kb[(kb0 + 0 + half * 32 + 16 + l15) * 32 + g * 8];
      f32x4 sA[2], sB[2];
      sA[0] = MFMA16(qf[0], kfA, zero4); sA[1] = MFMA16(qf[1], kfA, zero4);
      sB[0] = MFMA16(qf[0], kfB, zero4); sB[1] = MFMA16(qf[1], kfB, zero4);
#pragma unroll
      for (int qt = 0; qt < 2; ++qt)
#pragma unroll
        for (int r = 0; r < 4; ++r) {
          float pA = exp2f(sA[qt][r]), pB = exp2f(sB[qt][r]);
          int row = qt * 16 + g * 4 + r;
          int x8 = (row & 7) << 3;
          P2[0][qg][row][((half * 2 + 0) * 16 + l15) ^ x8] = f2bf(pA);
          P2[0][qg][row][((half * 2 + 1) * 16 + l15) ^ x8] = f2bf(pB);
          float v = pA + pB;
          rsv[qt][r] = half ? (rsv[qt][r] + v) : v;
        }
    }
#pragma unroll
    for (int qt = 0; qt < 2; ++qt)
#pragma unroll
      for (int r = 0; r < 4; ++r) {
        float rs = rsv[qt][r];
        rs += __shfl_xor(rs, 1);
        rs += __shfl_xor(rs, 2);
        rs += __shfl_xor(rs, 4);
        rs += __shfl_xor(rs, 8);
        l_[qt][r] += rs;
      }
  }
  asm volatile("s_waitcnt vmcnt(0) lgkmcnt(0)" ::: "memory");
  __builtin_amdgcn_s_barrier();
  __builtin_amdgcn_sched_barrier(0);

  for (int kv = 0; kv < 4096; kv += 64) {
    const int buf = (kv >> 6) & 1;       // V buffer & P parity for tile t
    const bool more = (kv + 64) < 4096;

    // 1) DMA V(t+1) -> Vlds[buf^1] (PV(t-1) readers cleared by last barrier)
    if (more) {
      const char* gsrc = VBb + (size_t)((kv >> 6) + 1) * 65536 + w * 8192 + lane * 16;
      char* ldst = (char*)&Vlds[buf ^ 1][0] + w * 8192;
#pragma unroll
      for (int j = 0; j < 8; ++j) gld_lds16(gsrc + j * 1024, ldst + j * 1024);
    }

    // 2) chh0: K(t+1) loads issued early (latency hides under preread+PV)
    short8 kfA, kfB, kfC, kfD;
    if (chh == 0 && more) {
      kfA = *(const short8*)&Kb[(kb0 + kv + 64 + 0 + l15) * 32 + g * 8];
      kfB = *(const short8*)&Kb[(kb0 + kv + 64 + 16 + l15) * 32 + g * 8];
      kfC = *(const short8*)&Kb[(kb0 + kv + 64 + 32 + l15) * 32 + g * 8];
      kfD = *(const short8*)&Kb[(kb0 + kv + 64 + 48 + l15) * 32 + g * 8];
    }

    // 3) pf(t) preread from P2[buf] (no barrier needed — dbuf by parity)
    short8 pf[2][2];
#pragma unroll
    for (int qt = 0; qt < 2; ++qt) {
      int row = qt * 16 + l15;
      int x8 = (l15 & 7) << 3;
#pragma unroll
      for (int k2 = 0; k2 < 2; ++k2)
        pf[qt][k2] = *(const short8*)&P2[buf][qg][row][(k2 * 32 + g * 8) ^ x8];
    }

    // 4) chh0: S+softmax(t+1) into P2[buf^1] (overlaps chh1's PV via TLP)
    if (chh == 0 && more) {
      f32x4 sA[2], sB[2], sC[2], sD[2];
      sA[0] = MFMA16(qf[0], kfA, zero4); sA[1] = MFMA16(qf[1], kfA, zero4);
      sB[0] = MFMA16(qf[0], kfB, zero4); sB[1] = MFMA16(qf[1], kfB, zero4);
      sC[0] = MFMA16(qf[0], kfC, zero4); sC[1] = MFMA16(qf[1], kfC, zero4);
      sD[0] = MFMA16(qf[0], kfD, zero4); sD[1] = MFMA16(qf[1], kfD, zero4);
#pragma unroll
      for (int qt = 0; qt < 2; ++qt)
#pragma unroll
        for (int r = 0; r < 4; ++r) {
          float pA = exp2f(sA[qt][r]), pB = exp2f(sB[qt][r]);
          float pC = exp2f(sC[qt][r]), pD = exp2f(sD[qt][r]);
          int row = qt * 16 + g * 4 + r;
          int x8 = (row & 7) << 3;
          P2[buf ^ 1][qg][row][(0 * 16 + l15) ^ x8] = f2bf(pA);
          P2[buf ^ 1][qg][row][(1 * 16 + l15) ^ x8] = f2bf(pB);
          P2[buf ^ 1][qg][row][(2 * 16 + l15) ^ x8] = f2bf(pC);
          P2[buf ^ 1][qg][row][(3 * 16 + l15) ^ x8] = f2bf(pD);
          float rs = (pA + pB) + (pC + pD);
          rs += __shfl_xor(rs, 1);
          rs += __shfl_xor(rs, 2);
          rs += __shfl_xor(rs, 4);
          rs += __shfl_xor(rs, 8);
          l_[qt][r] += rs;
        }
    }

    // 5) PV(t): both ch-halves, V from Vlds[buf], P from pre-read pf
#pragma unroll
    for (int ct = 0; ct < 16; ++ct) {
      int c = chb + ct * 16 + l15;
      int sw = (c & 7) << 4;
      const char* vrow = (const char*)&Vlds[buf][0] + c * 128;
      short8 vf0 = *(const short8*)(vrow + ((g * 16) ^ sw));
      short8 vf1 = *(const short8*)(vrow + ((64 + g * 16) ^ sw));
      acc[0][ct] = MFMA16(pf[0][0], vf0, acc[0][ct]);
      acc[0][ct] = MFMA16(pf[0][1], vf1, acc[0][ct]);
      acc[1][ct] = MFMA16(pf[1][0], vf0, acc[1][ct]);
      acc[1][ct] = MFMA16(pf[1][1], vf1, acc[1][ct]);
    }

    // 6) single end barrier: P(t+1)+V(t+1) visible; PV(t)/pf(t) reads done
    asm volatile("s_waitcnt vmcnt(0) lgkmcnt(0)" ::: "memory");
    __builtin_amdgcn_s_barrier();
    __builtin_amdgcn_sched_barrier(0);
  }

  // ---- epilogue part 1: share row sums (lsum overlays dead P2) ----
  float* lsum = (float*)&P2[0][0][0][0];   // [4][32]
  if (chh == 0 && l15 == 0) {
#pragma unroll
    for (int qt = 0; qt < 2; ++qt)
#pragma unroll
      for (int r = 0; r < 4; ++r)
        lsum[qg * 32 + qt * 16 + g * 4 + r] = l_[qt][r];
  }
  __syncthreads();

  // ---- epilogue part 2: normalize AO into LDS (reuse Vlds) ----
  // AO layout: [n 0..127][c 0..511] u16, 1KB rows, elem col ^= ((n&7)<<3).
  u16* AO = (u16*)&Vlds[0][0];
#pragma unroll
  for (int qt = 0; qt < 2; ++qt) {
    float inv[4];
#pragma unroll
    for (int r = 0; r < 4; ++r) inv[r] = 1.0f / lsum[qg * 32 + qt * 16 + g * 4 + r];
#pragma unroll
    for (int ct = 0; ct < 16; ++ct)
#pragma unroll
      for (int r = 0; r < 4; ++r) {
        int nrow = qg * 32 + qt * 16 + g * 4 + r;   // block-local q row
        int c = chb + ct * 16 + l15;
        AO[nrow * 512 + (c ^ ((nrow & 7) << 3))] = f2bf(acc[qt][ct][r] * inv[r]);
      }
  }
  __syncthreads();

  // ---- epilogue part 3: out = gamma*(Wo @ AO + bo) + x ----
  // wave w: o rows w*64 .. w*64+63; n = qblk .. qblk+127.
  f32x4 oacc[4][8];
#pragma unroll
  for (int ot = 0; ot < 4; ++ot)
#pragma unroll
    for (int nt = 0; nt < 8; ++nt) oacc[ot][nt] = zero4;

  for (int c0 = 0; c0 < 512; c0 += 64) {
#pragma unroll
    for (int nth = 0; nth < 2; ++nth) {     // nt halves to bound reg pressure
      short8 bb[4][2];
#pragma unroll
      for (int n2 = 0; n2 < 4; ++n2)
#pragma unroll
        for (int ks = 0; ks < 2; ++ks) {
          int row = (nth * 4 + n2) * 16 + l15;
          int coff = (c0 + ks * 32 + g * 8) ^ ((row & 7) << 3);
          bb[n2][ks] = *(const short8*)&AO[row * 512 + coff];
        }
#pragma unroll
      for (int ot = 0; ot < 4; ++ot) {
        short8 af[2];
#pragma unroll
        for (int ks = 0; ks < 2; ++ks)
          af[ks] = *(const short8*)&Wob[(size_t)(w * 64 + ot * 16 + l15) * 512 + c0 + ks * 32 + g * 8];
#pragma unroll
        for (int ks = 0; ks < 2; ++ks)
#pragma unroll
          for (int n2 = 0; n2 < 4; ++n2)
            oacc[ot][nth * 4 + n2] = MFMA16(af[ks], bb[n2][ks], oacc[ot][nth * 4 + n2]);
      }
    }
  }

  float gm = gamma[0];
#pragma unroll
  for (int ot = 0; ot < 4; ++ot)
#pragma unroll
    for (int nt = 0; nt < 8; ++nt)
#pragma unroll
      for (int r = 0; r < 4; ++r) {
        int o = w * 64 + ot * 16 + g * 4 + r;
        int n = qblk + nt * 16 + l15;
        size_t idx = ((size_t)(b * 512 + o)) * 4096 + n;
        out[idx] = gm * (oacc[ot][nt][r] + bo[o]) + x[idx];
      }
}

// ---------------------------------------------------------------------------
// Workspace map (38.9 MB):
//   V2 ws+0 (32MB, swizzled-tile V) | Qb ws+32M (2MB) | Kb ws+34M (2MB)
//   Wvb +36M (0.5MB) | Wob (0.5MB) | Wqkb (64KB)
//   d_out holds ONLY the final fp32 output (attn_f writes it directly).
// ---------------------------------------------------------------------------
extern "C" void kernel_launch(void* const* d_in, const int* in_sizes, int n_in,
                              void* d_out, int out_size, void* d_ws, size_t ws_size,
                              hipStream_t stream) {
  (void)in_sizes; (void)n_in; (void)out_size; (void)ws_size;
  const float* x     = (const float*)d_in[0];
  const float* Wq    = (const float*)d_in[1];
  const float* bq    = (const float*)d_in[2];
  const float* Wk    = (const float*)d_in[3];
  const float* bk    = (const float*)d_in[4];
  const float* Wv    = (const float*)d_in[5];
  const float* bv    = (const float*)d_in[6];
  const float* Wo    = (const float*)d_in[7];
  const float* bo    = (const float*)d_in[8];
  const float* gamma = (const float*)d_in[9];

  char* wsb = (char*)d_ws;
  u16* V2   = (u16*)(wsb + 0);
  u16* Qb   = (u16*)(wsb + (size_t)33554432);
  u16* Kb   = (u16*)(wsb + (size_t)35651584);
  u16* Wvb  = (u16*)(wsb + (size_t)37748736);
  u16* Wob  = (u16*)(wsb + (size_t)38273024);
  u16* Wqkb = (u16*)(wsb + (size_t)38797312);

  conv_all<<<544, 256, 0, stream>>>(Wv, Wo, Wq, Wk, Wvb, Wob, Wqkb);
  qkv_proj<<<dim3(64, 8, 2), 256, 0, stream>>>(x, Wvb, Wqkb, bv, bq, bk, V2, Qb, Kb);
  attn_f<<<256, 512, 0, stream>>>(Qb, Kb, V2, Wob, bo, gamma, x, (float*)d_out);
}

// Round 22
// 325.008 us; speedup vs baseline: 1.0689x; 1.0689x over previous
//
#include <hip/hip_runtime.h>
#include <stdint.h>

typedef unsigned short u16;
typedef float f32x4 __attribute__((ext_vector_type(4)));
typedef short short8 __attribute__((ext_vector_type(8)));  // 8 bf16 in 4 VGPRs

__device__ __forceinline__ u16 f2bf(float f) {
  union { float f; uint32_t u; } v; v.f = f;
  return (u16)((v.u + 0x7FFFu + ((v.u >> 16) & 1u)) >> 16);
}
__device__ __forceinline__ uint32_t pack2(u16 lo, u16 hi) {
  return (uint32_t)lo | ((uint32_t)hi << 16);
}
// Async global->LDS DMA, 16B/lane: LDS dest = wave-uniform base + lane*16,
// global src = per-lane address. Zero VGPR staging.
__device__ __forceinline__ void gld_lds16(const void* gsrc, void* ldst) {
  __builtin_amdgcn_global_load_lds(
      (const __attribute__((address_space(1))) unsigned int*)gsrc,
      (__attribute__((address_space(3))) unsigned int*)ldst, 16, 0, 0);
}

#define MFMA16(a, b, c) __builtin_amdgcn_mfma_f32_16x16x32_bf16((a), (b), (c), 0, 0, 0)

// ---------------------------------------------------------------------------
// Merged weight conversion: Wv (64K f4), Wo (64K f4), Wqk (8K f4, Q x log2e).
// ---------------------------------------------------------------------------
__global__ void conv_all(const float* __restrict__ Wv, const float* __restrict__ Wo,
                         const float* __restrict__ Wq, const float* __restrict__ Wk,
                         u16* __restrict__ Wvb, u16* __restrict__ Wob,
                         u16* __restrict__ Wqkb) {
  int i = blockIdx.x * blockDim.x + threadIdx.x;  // float4 index, 139264 total
  if (i >= 139264) return;
  const float LOG2E = 1.4426950408889634f;
  float4 v;
  u16* dst;
  int di;
  float s = 1.0f;
  if (i < 65536) {
    v = ((const float4*)Wv)[i]; dst = Wvb; di = i;
  } else if (i < 131072) {
    v = ((const float4*)Wo)[i - 65536]; dst = Wob; di = i - 65536;
  } else {
    int j = i - 131072;
    bool isQ = j < 4096;
    v = isQ ? ((const float4*)Wq)[j] : ((const float4*)Wk)[j - 4096];
    s = isQ ? LOG2E : 1.0f;
    dst = Wqkb; di = j;
  }
  uint2 p;
  p.x = pack2(f2bf(v.x * s), f2bf(v.y * s));
  p.y = pack2(f2bf(v.z * s), f2bf(v.w * s));
  ((uint2*)dst)[di] = p;
}

// ---------------------------------------------------------------------------
// Fused QKV projection, OG-SPLIT (round 20, verified): grid z in {0,1},
// 4 og-groups each; z=0 also computes Q/K. x prefetch ping-pong.
// ---------------------------------------------------------------------------
__global__ __launch_bounds__(256) void qkv_proj(
    const float* __restrict__ x, const u16* __restrict__ Wvb,
    const u16* __restrict__ Wqkb, const float* __restrict__ bv,
    const float* __restrict__ bq, const float* __restrict__ bk,
    u16* __restrict__ V2, u16* __restrict__ Qb, u16* __restrict__ Kb) {
  const int b = blockIdx.y, nb = blockIdx.x * 64;
  const int oh = blockIdx.z;               // og half: 0 -> og 0..3 (+QK), 1 -> og 4..7
  const int t = threadIdx.x, w = t >> 6, lane = t & 63, g = lane >> 4, l15 = lane & 15;
  const int wo = (w >> 1) * 32, wn = (w & 1) * 32;
  __shared__ __align__(16) u16 xT[64][64];  // row = n (128B rows), swizzled

  f32x4 zero4 = {0.f, 0.f, 0.f, 0.f};
  f32x4 acc[4][2][2];
#pragma unroll
  for (int og = 0; og < 4; ++og)
#pragma unroll
    for (int ot = 0; ot < 2; ++ot)
#pragma unroll
      for (int nt = 0; nt < 2; ++nt) acc[og][ot][nt] = zero4;
  f32x4 accq[2][2];
  accq[0][0] = zero4; accq[0][1] = zero4; accq[1][0] = zero4; accq[1][1] = zero4;

  const int cq4 = (t >> 4) * 4, n4 = (t & 15) * 4;
  const size_t xrow = (size_t)(b * 512) * 4096 + nb + n4;

  float4 cur0 = *(const float4*)&x[xrow + (size_t)(cq4 + 0) * 4096];
  float4 cur1 = *(const float4*)&x[xrow + (size_t)(cq4 + 1) * 4096];
  float4 cur2 = *(const float4*)&x[xrow + (size_t)(cq4 + 2) * 4096];
  float4 cur3 = *(const float4*)&x[xrow + (size_t)(cq4 + 3) * 4096];

#pragma unroll
  for (int ci = 0; ci < 8; ++ci) {
    const int c0 = ci * 64;
    float4 nxt0, nxt1, nxt2, nxt3;
    if (ci < 7) {
      nxt0 = *(const float4*)&x[xrow + (size_t)(c0 + 64 + cq4 + 0) * 4096];
      nxt1 = *(const float4*)&x[xrow + (size_t)(c0 + 64 + cq4 + 1) * 4096];
      nxt2 = *(const float4*)&x[xrow + (size_t)(c0 + 64 + cq4 + 2) * 4096];
      nxt3 = *(const float4*)&x[xrow + (size_t)(c0 + 64 + cq4 + 3) * 4096];
    }
    float rr[4][4];
    rr[0][0] = cur0.x; rr[0][1] = cur0.y; rr[0][2] = cur0.z; rr[0][3] = cur0.w;
    rr[1][0] = cur1.x; rr[1][1] = cur1.y; rr[1][2] = cur1.z; rr[1][3] = cur1.w;
    rr[2][0] = cur2.x; rr[2][1] = cur2.y; rr[2][2] = cur2.z; rr[2][3] = cur2.w;
    rr[3][0] = cur3.x; rr[3][1] = cur3.y; rr[3][2] = cur3.z; rr[3][3] = cur3.w;
#pragma unroll
    for (int k = 0; k < 4; ++k) {
      int row = n4 + k;
      uint2 pk;
      pk.x = pack2(f2bf(rr[0][k]), f2bf(rr[1][k]));
      pk.y = pack2(f2bf(rr[2][k]), f2bf(rr[3][k]));
      int byte = row * 128 + ((cq4 * 2) ^ ((row & 7) << 4));
      *(uint2*)((char*)&xT[0][0] + byte) = pk;
    }
    __syncthreads();

    short8 bb[2][2];
#pragma unroll
    for (int nt = 0; nt < 2; ++nt)
#pragma unroll
      for (int ks = 0; ks < 2; ++ks) {
        int row = wn + nt * 16 + l15;
        int byte = row * 128 + (((ks * 64) + (g * 16)) ^ ((row & 7) << 4));
        bb[nt][ks] = *(const short8*)((const char*)&xT[0][0] + byte);
      }
#pragma unroll
    for (int og = 0; og < 4; ++og) {
      short8 af[2][2];
#pragma unroll
      for (int ot = 0; ot < 2; ++ot)
#pragma unroll
        for (int ks = 0; ks < 2; ++ks)
          af[ot][ks] = *(const short8*)&Wvb[(size_t)((oh * 4 + og) * 64 + wo + ot * 16 + l15) * 512 + c0 + ks * 32 + g * 8];
#pragma unroll
      for (int ks = 0; ks < 2; ++ks)
#pragma unroll
        for (int ot = 0; ot < 2; ++ot)
#pragma unroll
          for (int nt = 0; nt < 2; ++nt)
            acc[og][ot][nt] = MFMA16(af[ot][ks], bb[nt][ks], acc[og][ot][nt]);
    }
    if (oh == 0) {
      short8 aq[2][2];
#pragma unroll
      for (int ot = 0; ot < 2; ++ot)
#pragma unroll
        for (int ks = 0; ks < 2; ++ks)
          aq[ot][ks] = *(const short8*)&Wqkb[(size_t)(wo + ot * 16 + l15) * 512 + c0 + ks * 32 + g * 8];
#pragma unroll
      for (int ks = 0; ks < 2; ++ks)
#pragma unroll
        for (int ot = 0; ot < 2; ++ot)
#pragma unroll
          for (int nt = 0; nt < 2; ++nt)
            accq[ot][nt] = MFMA16(aq[ot][ks], bb[nt][ks], accq[ot][nt]);
    }
    __syncthreads();
    if (ci < 7) { cur0 = nxt0; cur1 = nxt1; cur2 = nxt2; cur3 = nxt3; }
  }

  const size_t tbase = (size_t)b * 2097152 + (size_t)(nb >> 6) * 32768;
#pragma unroll
  for (int og = 0; og < 4; ++og)
#pragma unroll
    for (int ot = 0; ot < 2; ++ot)
#pragma unroll
      for (int nt = 0; nt < 2; ++nt)
#pragma unroll
        for (int r = 0; r < 4; ++r) {
          int o = (oh * 4 + og) * 64 + wo + ot * 16 + g * 4 + r;
          int kk = wn + nt * 16 + l15;
          int swz = ((kk * 2) ^ ((o & 7) << 4)) >> 1;
          V2[tbase + o * 64 + swz] = f2bf(acc[og][ot][nt][r] + bv[o]);
        }
  if (oh == 0) {
    const float LOG2E = 1.4426950408889634f;
#pragma unroll
    for (int ot = 0; ot < 2; ++ot)
#pragma unroll
      for (int nt = 0; nt < 2; ++nt)
#pragma unroll
        for (int r = 0; r < 4; ++r) {
          int o = wo + ot * 16 + g * 4 + r;   // 0..63: Q rows then K rows
          int n = nb + wn + nt * 16 + l15;
          if (o < 32) {
            Qb[((size_t)(b * 4096 + n)) * 32 + o] = f2bf(accq[ot][nt][r] + bq[o] * LOG2E);
          } else {
            Kb[((size_t)(b * 4096 + n)) * 32 + (o - 32)] = f2bf(accq[ot][nt][r] + bk[o - 32]);
          }
        }
  }
}

// ---------------------------------------------------------------------------
// Fused flash attention + Wo projection + residual, SOFTMAX-PIPELINED
// (round-16 structure, verified 251us — local optimum across 6 tested
// variants: counted-vmcnt null; setprio/uniform-softmax/64q-retile/
// 16-wave/single-barrier all regressed). 8 waves (qg=w&3 32q, chh=w>>2
// 256ch); chh0: S+softmax; pf(t) pre-read -> mid-barrier -> S+P(t+1)
// overlapping PV(t) via TLP -> end barrier.
// ---------------------------------------------------------------------------
__global__ __launch_bounds__(512, 1) void attn_f(
    const u16* __restrict__ Qb, const u16* __restrict__ Kb,
    const u16* __restrict__ V2, const u16* __restrict__ Wob,
    const float* __restrict__ bo, const float* __restrict__ gamma,
    const float* __restrict__ x, float* __restrict__ out) {
  const int bid = blockIdx.x;
  const int b = bid & 7;                 // XCD-pinned batch
  const int qblk = (bid >> 3) * 128;
  const int t = threadIdx.x;
  const int w = t >> 6, lane = t & 63, g = lane >> 4, l15 = lane & 15;
  const int qg = w & 3, chh = w >> 2;    // SIMD i hosts (qg=i,chh=0)+(qg=i,chh=1)
  const int qbase = qblk + qg * 32;
  const int chb = chh * 256;

  __shared__ __align__(16) u16 Vlds[2][32768];   // [buf][512ch][64k]; reused as AO
  __shared__ __align__(16) u16 Plds[4][32][88];  // per q-group, shared
  __shared__ float lsum[4][32];

  f32x4 zero4 = {0.f, 0.f, 0.f, 0.f};

  short8 qf[2];
  if (chh == 0) {
#pragma unroll
    for (int qt = 0; qt < 2; ++qt)
      qf[qt] = *(const short8*)&Qb[((size_t)(b * 4096 + qbase + qt * 16 + l15)) * 32 + g * 8];
  }

  f32x4 acc[2][16];
#pragma unroll
  for (int qt = 0; qt < 2; ++qt)
#pragma unroll
    for (int ct = 0; ct < 16; ++ct) acc[qt][ct] = zero4;
  float l_[2][4] = {{0.f, 0.f, 0.f, 0.f}, {0.f, 0.f, 0.f, 0.f}};

  const char* VBb = (const char*)(V2 + (size_t)b * 2097152);  // byte base
  const size_t kb0 = (size_t)b * 4096;

  // ---- prologue: DMA V(0); chh0 builds P(0) ----
  {
    const char* gsrc = VBb + w * 8192 + lane * 16;
    char* ldst = (char*)&Vlds[0][0] + w * 8192;
#pragma unroll
    for (int j = 0; j < 8; ++j) gld_lds16(gsrc + j * 1024, ldst + j * 1024);
  }
  if (chh == 0) {
    float rsv[2][4];
#pragma unroll
    for (int half = 0; half < 2; ++half) {
      short8 kfA = *(const short8*)&Kb[(kb0 + 0 + half * 32 + 0 + l15) * 32 + g * 8];
      short8 kfB = *(const short8*)&Kb[(kb0 + 0 + half * 32 + 16 + l15) * 32 + g * 8];
      f32x4 sA[2], sB[2];
      sA[0] = MFMA16(qf[0], kfA, zero4); sA[1] = MFMA16(qf[1], kfA, zero4);
      sB[0] = MFMA16(qf[0], kfB, zero4); sB[1] = MFMA16(qf[1], kfB, zero4);
#pragma unroll
      for (int qt = 0; qt < 2; ++qt)
#pragma unroll
        for (int r = 0; r < 4; ++r) {
          float pA = exp2f(sA[qt][r]), pB = exp2f(sB[qt][r]);
          Plds[qg][qt * 16 + g * 4 + r][(half * 2 + 0) * 16 + l15] = f2bf(pA);
          Plds[qg][qt * 16 + g * 4 + r][(half * 2 + 1) * 16 + l15] = f2bf(pB);
          float v = pA + pB;
          rsv[qt][r] = half ? (rsv[qt][r] + v) : v;
        }
    }
#pragma unroll
    for (int qt = 0; qt < 2; ++qt)
#pragma unroll
      for (int r = 0; r < 4; ++r) {
        float rs = rsv[qt][r];
        rs += __shfl_xor(rs, 1);
        rs += __shfl_xor(rs, 2);
        rs += __shfl_xor(rs, 4);
        rs += __shfl_xor(rs, 8);
        l_[qt][r] += rs;
      }
  }
  asm volatile("s_waitcnt vmcnt(0) lgkmcnt(0)" ::: "memory");
  __builtin_amdgcn_s_barrier();
  __builtin_amdgcn_sched_barrier(0);

  for (int kv = 0; kv < 4096; kv += 64) {
    const int buf = (kv >> 6) & 1;
    const bool more = (kv + 64) < 4096;

    // 1) DMA V(t+1) -> buf^1 (its old content V(t-1) freed by end barrier)
    if (more) {
      const char* gsrc = VBb + (size_t)((kv >> 6) + 1) * 65536 + w * 8192 + lane * 16;
      char* ldst = (char*)&Vlds[buf ^ 1][0] + w * 8192;
#pragma unroll
      for (int j = 0; j < 8; ++j) gld_lds16(gsrc + j * 1024, ldst + j * 1024);
    }

    // 2) pre-read pf(t) — after this Plds is dead
    short8 pf[2][2];
#pragma unroll
    for (int qt = 0; qt < 2; ++qt)
#pragma unroll
      for (int k2 = 0; k2 < 2; ++k2)
        pf[qt][k2] = *(const short8*)&Plds[qg][qt * 16 + l15][k2 * 32 + g * 8];

    // mid-barrier: pf consumed by all waves; Plds free for P(t+1)
    asm volatile("s_waitcnt lgkmcnt(0)" ::: "memory");
    __builtin_amdgcn_s_barrier();
    __builtin_amdgcn_sched_barrier(0);

    // 3) chh0: S+softmax(t+1) into Plds (overlaps PV(t) via chh1's TLP)
    if (chh == 0 && more) {
      float rsv[2][4];
#pragma unroll
      for (int half = 0; half < 2; ++half) {
        short8 kfA = *(const short8*)&Kb[(kb0 + kv + 64 + half * 32 + 0 + l15) * 32 + g * 8];
        short8 kfB = *(const short8*)&Kb[(kb0 + kv + 64 + half * 32 + 16 + l15) * 32 + g * 8];
        f32x4 sA[2], sB[2];
        sA[0] = MFMA16(qf[0], kfA, zero4); sA[1] = MFMA16(qf[1], kfA, zero4);
        sB[0] = MFMA16(qf[0], kfB, zero4); sB[1] = MFMA16(qf[1], kfB, zero4);
#pragma unroll
        for (int qt = 0; qt < 2; ++qt)
#pragma unroll
          for (int r = 0; r < 4; ++r) {
            float pA = exp2f(sA[qt][r]), pB = exp2f(sB[qt][r]);
            Plds[qg][qt * 16 + g * 4 + r][(half * 2 + 0) * 16 + l15] = f2bf(pA);
            Plds[qg][qt * 16 + g * 4 + r][(half * 2 + 1) * 16 + l15] = f2bf(pB);
            float v = pA + pB;
            rsv[qt][r] = half ? (rsv[qt][r] + v) : v;
          }
      }
#pragma unroll
      for (int qt = 0; qt < 2; ++qt)
#pragma unroll
        for (int r = 0; r < 4; ++r) {
          float rs = rsv[qt][r];
          rs += __shfl_xor(rs, 1);
          rs += __shfl_xor(rs, 2);
          rs += __shfl_xor(rs, 4);
          rs += __shfl_xor(rs, 8);
          l_[qt][r] += rs;
        }
    }

    // 4) PV(t): both ch-halves, V from Vlds[buf], P from pre-read pf
#pragma unroll
    for (int ct = 0; ct < 16; ++ct) {
      int c = chb + ct * 16 + l15;
      int sw = (c & 7) << 4;
      const char* vrow = (const char*)&Vlds[buf][0] + c * 128;
      short8 vf0 = *(const short8*)(vrow + ((g * 16) ^ sw));
      short8 vf1 = *(const short8*)(vrow + ((64 + g * 16) ^ sw));
      acc[0][ct] = MFMA16(pf[0][0], vf0, acc[0][ct]);
      acc[0][ct] = MFMA16(pf[0][1], vf1, acc[0][ct]);
      acc[1][ct] = MFMA16(pf[1][0], vf0, acc[1][ct]);
      acc[1][ct] = MFMA16(pf[1][1], vf1, acc[1][ct]);
    }

    // end barrier: P(t+1) visible, PV(t) LDS reads done, DMA(t+1) retired
    asm volatile("s_waitcnt vmcnt(0) lgkmcnt(0)" ::: "memory");
    __builtin_amdgcn_s_barrier();
    __builtin_amdgcn_sched_barrier(0);
  }

  // ---- epilogue part 1: share row sums ----
  if (chh == 0 && l15 == 0) {
#pragma unroll
    for (int qt = 0; qt < 2; ++qt)
#pragma unroll
      for (int r = 0; r < 4; ++r)
        lsum[qg][qt * 16 + g * 4 + r] = l_[qt][r];
  }
  __syncthreads();

  // ---- epilogue part 2: normalize AO into LDS (reuse Vlds) ----
  // AO layout: [n 0..127][c 0..511] u16, 1KB rows, elem col ^= ((n&7)<<3).
  u16* AO = (u16*)&Vlds[0][0];
#pragma unroll
  for (int qt = 0; qt < 2; ++qt) {
    float inv[4];
#pragma unroll
    for (int r = 0; r < 4; ++r) inv[r] = 1.0f / lsum[qg][qt * 16 + g * 4 + r];
#pragma unroll
    for (int ct = 0; ct < 16; ++ct)
#pragma unroll
      for (int r = 0; r < 4; ++r) {
        int nrow = qg * 32 + qt * 16 + g * 4 + r;   // block-local q row
        int c = chb + ct * 16 + l15;
        AO[nrow * 512 + (c ^ ((nrow & 7) << 3))] = f2bf(acc[qt][ct][r] * inv[r]);
      }
  }
  __syncthreads();

  // ---- epilogue part 3: out = gamma*(Wo @ AO + bo) + x ----
  // wave w: o rows w*64 .. w*64+63; n = qblk .. qblk+127.
  f32x4 oacc[4][8];
#pragma unroll
  for (int ot = 0; ot < 4; ++ot)
#pragma unroll
    for (int nt = 0; nt < 8; ++nt) oacc[ot][nt] = zero4;

  for (int c0 = 0; c0 < 512; c0 += 64) {
#pragma unroll
    for (int nth = 0; nth < 2; ++nth) {     // nt halves to bound reg pressure
      short8 bb[4][2];
#pragma unroll
      for (int n2 = 0; n2 < 4; ++n2)
#pragma unroll
        for (int ks = 0; ks < 2; ++ks) {
          int row = (nth * 4 + n2) * 16 + l15;
          int coff = (c0 + ks * 32 + g * 8) ^ ((row & 7) << 3);
          bb[n2][ks] = *(const short8*)&AO[row * 512 + coff];
        }
#pragma unroll
      for (int ot = 0; ot < 4; ++ot) {
        short8 af[2];
#pragma unroll
        for (int ks = 0; ks < 2; ++ks)
          af[ks] = *(const short8*)&Wob[(size_t)(w * 64 + ot * 16 + l15) * 512 + c0 + ks * 32 + g * 8];
#pragma unroll
        for (int ks = 0; ks < 2; ++ks)
#pragma unroll
          for (int n2 = 0; n2 < 4; ++n2)
            oacc[ot][nth * 4 + n2] = MFMA16(af[ks], bb[n2][ks], oacc[ot][nth * 4 + n2]);
      }
    }
  }

  float gm = gamma[0];
#pragma unroll
  for (int ot = 0; ot < 4; ++ot)
#pragma unroll
    for (int nt = 0; nt < 8; ++nt)
#pragma unroll
      for (int r = 0; r < 4; ++r) {
        int o = w * 64 + ot * 16 + g * 4 + r;
        int n = qblk + nt * 16 + l15;
        size_t idx = ((size_t)(b * 512 + o)) * 4096 + n;
        out[idx] = gm * (oacc[ot][nt][r] + bo[o]) + x[idx];
      }
}

// ---------------------------------------------------------------------------
// Workspace map (38.9 MB):
//   V2 ws+0 (32MB, swizzled-tile V) | Qb ws+32M (2MB) | Kb ws+34M (2MB)
//   Wvb +36M (0.5MB) | Wob (0.5MB) | Wqkb (64KB)
//   d_out holds ONLY the final fp32 output (attn_f writes it directly).
// ---------------------------------------------------------------------------
extern "C" void kernel_launch(void* const* d_in, const int* in_sizes, int n_in,
                              void* d_out, int out_size, void* d_ws, size_t ws_size,
                              hipStream_t stream) {
  (void)in_sizes; (void)n_in; (void)out_size; (void)ws_size;
  const float* x     = (const float*)d_in[0];
  const float* Wq    = (const float*)d_in[1];
  const float* bq    = (const float*)d_in[2];
  const float* Wk    = (const float*)d_in[3];
  const float* bk    = (const float*)d_in[4];
  const float* Wv    = (const float*)d_in[5];
  const float* bv    = (const float*)d_in[6];
  const float* Wo    = (const float*)d_in[7];
  const float* bo    = (const float*)d_in[8];
  const float* gamma = (const float*)d_in[9];

  char* wsb = (char*)d_ws;
  u16* V2   = (u16*)(wsb + 0);
  u16* Qb   = (u16*)(wsb + (size_t)33554432);
  u16* Kb   = (u16*)(wsb + (size_t)35651584);
  u16* Wvb  = (u16*)(wsb + (size_t)37748736);
  u16* Wob  = (u16*)(wsb + (size_t)38273024);
  u16* Wqkb = (u16*)(wsb + (size_t)38797312);

  conv_all<<<544, 256, 0, stream>>>(Wv, Wo, Wq, Wk, Wvb, Wob, Wqkb);
  qkv_proj<<<dim3(64, 8, 2), 256, 0, stream>>>(x, Wvb, Wqkb, bv, bq, bk, V2, Qb, Kb);
  attn_f<<<256, 512, 0, stream>>>(Qb, Kb, V2, Wob, bo, gamma, x, (float*)d_out);
}